// Round 2
// baseline (1208.093 us; speedup 1.0000x reference)
//
#include <hip/hip_runtime.h>
#include <cmath>

typedef __bf16 bf16_t;
typedef __bf16 bf16x8 __attribute__((ext_vector_type(8)));
typedef __bf16 bf16x4 __attribute__((ext_vector_type(4)));
typedef float f32x4 __attribute__((ext_vector_type(4)));

#define DEV_INLINE __device__ __forceinline__

DEV_INLINE void gload_lds16(const void* g, void* l) {
  __builtin_amdgcn_global_load_lds(
      (const __attribute__((address_space(1))) void*)g,
      (__attribute__((address_space(3))) void*)l, 16, 0, 0);
}

// ---------------------------------------------------------------------------
// GEMM: C = A[M][K] * B^T  (B stored [N][K]) + bias, with fused epilogue.
// EPI: 0 = fp32 out, 1 = bf16 out, 2 = bf16 out *scale, 3 = bf16 gelu(out)
// 128x128 tile, BK=32, 256 threads = 4 waves (2x2), wave tile 64x64 (4x4 frags)
// ---------------------------------------------------------------------------
template<int EPI, bool HAS_BIAS>
__global__ __launch_bounds__(256)
void gemm_bt(const bf16_t* __restrict__ A, const bf16_t* __restrict__ B,
             const float* __restrict__ bias, void* __restrict__ C,
             int M, int N, int K,
             long sA, long sB, long sC, float scale)
{
  __shared__ alignas(16) bf16_t As[128 * 32];
  __shared__ alignas(16) bf16_t Bs[128 * 32];
  const int b = blockIdx.z;
  A += (long)b * sA;
  B += (long)b * sB;
  const int t  = threadIdx.x;
  const int l  = t & 63;
  const int w  = t >> 6;
  const int wr = (w >> 1) * 64;   // wave row offset in tile
  const int wc = (w & 1) * 64;    // wave col offset in tile
  const int m0 = blockIdx.y * 128;
  const int n0 = blockIdx.x * 128;

  // staging: thread t loads 16B chunks; LDS dest is wave-uniform base + lane*16.
  const int srow = t >> 2;
  const int scol = (t & 3) * 8;
  const bf16_t* ga0 = A + (long)(m0 + srow) * K + scol;
  const bf16_t* ga1 = A + (long)(m0 + 64 + srow) * K + scol;
  const bf16_t* gb0 = B + (long)(n0 + srow) * K + scol;
  const bf16_t* gb1 = B + (long)(n0 + 64 + srow) * K + scol;
  bf16_t* lA0 = &As[t * 8];
  bf16_t* lA1 = &As[2048 + t * 8];
  bf16_t* lB0 = &Bs[t * 8];
  bf16_t* lB1 = &Bs[2048 + t * 8];

  f32x4 acc[4][4] = {};

  const int fr = l & 15;         // fragment row (A) / col (B) within 16
  const int kk = (l >> 4) * 8;   // k offset within 32

  for (int k0 = 0; k0 < K; k0 += 32) {
    gload_lds16(ga0 + k0, lA0);
    gload_lds16(ga1 + k0, lA1);
    gload_lds16(gb0 + k0, lB0);
    gload_lds16(gb1 + k0, lB1);
    __syncthreads();
    bf16x8 af[4], bfr[4];
#pragma unroll
    for (int mi = 0; mi < 4; mi++)
      af[mi] = *(const bf16x8*)&As[(wr + mi * 16 + fr) * 32 + kk];
#pragma unroll
    for (int ni = 0; ni < 4; ni++)
      bfr[ni] = *(const bf16x8*)&Bs[(wc + ni * 16 + fr) * 32 + kk];
#pragma unroll
    for (int mi = 0; mi < 4; mi++)
#pragma unroll
      for (int ni = 0; ni < 4; ni++)
        acc[mi][ni] = __builtin_amdgcn_mfma_f32_16x16x32_bf16(
            af[mi], bfr[ni], acc[mi][ni], 0, 0, 0);
    __syncthreads();
  }

  // C/D layout: col = lane&15, row = 4*(lane>>4) + reg
  const long cb = (long)b * sC;
#pragma unroll
  for (int mi = 0; mi < 4; mi++) {
#pragma unroll
    for (int ni = 0; ni < 4; ni++) {
      const int c = n0 + wc + ni * 16 + fr;
      float bias_v = 0.f;
      if constexpr (HAS_BIAS) bias_v = bias[c];
#pragma unroll
      for (int r = 0; r < 4; r++) {
        const int row = m0 + wr + mi * 16 + (l >> 4) * 4 + r;
        float v = acc[mi][ni][r] + bias_v;
        if constexpr (EPI == 2) v *= scale;
        if constexpr (EPI == 3) v = 0.5f * v * (1.f + erff(v * 0.70710678118f));
        const long idx = cb + (long)row * N + c;
        if constexpr (EPI == 0) ((float*)C)[idx] = v;
        else                    ((bf16_t*)C)[idx] = (bf16_t)v;
      }
    }
  }
}

// ---------------------------------------------------------------------------
// Transpose + cast to bf16: in [R][Cc] (SrcT) -> out [Cc][R] (bf16), batched.
// ---------------------------------------------------------------------------
template<typename SrcT>
__global__ __launch_bounds__(256)
void transpose_cast(const SrcT* __restrict__ in, bf16_t* __restrict__ out,
                    int R, int Cc, long sIn, long sOut)
{
  __shared__ float tile[32][33];
  const int b = blockIdx.z;
  in  += (long)b * sIn;
  out += (long)b * sOut;
  const int c0 = blockIdx.x * 32;
  const int r0 = blockIdx.y * 32;
  const int tx = threadIdx.x & 31;
  const int ty = threadIdx.x >> 5;  // 0..7
#pragma unroll
  for (int i = 0; i < 32; i += 8)
    tile[ty + i][tx] = (float)in[(long)(r0 + ty + i) * Cc + (c0 + tx)];
  __syncthreads();
#pragma unroll
  for (int i = 0; i < 32; i += 8)
    out[(long)(c0 + ty + i) * R + (r0 + tx)] = (bf16_t)tile[tx][ty + i];
}

__global__ __launch_bounds__(256)
void cast_to_bf16(const float* __restrict__ in, bf16_t* __restrict__ out, long n)
{
  const long i = ((long)blockIdx.x * 256 + threadIdx.x) * 4;
  if (i >= n) return;
  const float4 v = *(const float4*)&in[i];
  bf16x4 o = { (bf16_t)v.x, (bf16_t)v.y, (bf16_t)v.z, (bf16_t)v.w };
  *(bf16x4*)&out[i] = o;
}

// ---------------------------------------------------------------------------
// Row softmax over 2048 bf16 elements, in place. One 256-thread block per row.
// ---------------------------------------------------------------------------
__global__ __launch_bounds__(256)
void softmax2048(bf16_t* __restrict__ E)
{
  const long row = blockIdx.x;
  bf16_t* p = E + row * 2048;
  const int t = threadIdx.x;
  bf16x8 xv = *(const bf16x8*)&p[t * 8];
  float v[8];
#pragma unroll
  for (int j = 0; j < 8; j++) v[j] = (float)xv[j];
  float m = v[0];
#pragma unroll
  for (int j = 1; j < 8; j++) m = fmaxf(m, v[j]);
  for (int o = 32; o; o >>= 1) m = fmaxf(m, __shfl_xor(m, o));
  __shared__ float redm[4];
  __shared__ float reds[4];
  if ((t & 63) == 0) redm[t >> 6] = m;
  __syncthreads();
  m = fmaxf(fmaxf(redm[0], redm[1]), fmaxf(redm[2], redm[3]));
  float s = 0.f;
#pragma unroll
  for (int j = 0; j < 8; j++) { v[j] = __expf(v[j] - m); s += v[j]; }
  for (int o = 32; o; o >>= 1) s += __shfl_xor(s, o);
  if ((t & 63) == 0) reds[t >> 6] = s;
  __syncthreads();
  s = reds[0] + reds[1] + reds[2] + reds[3];
  const float inv = 1.f / s;
  bf16x8 ov;
#pragma unroll
  for (int j = 0; j < 8; j++) ov[j] = (bf16_t)(v[j] * inv);
  *(bf16x8*)&p[t * 8] = ov;
}

// ---------------------------------------------------------------------------
// Fused residual add + LayerNorm over rows of 512.
// y = LN(xa + xadd) * g + be.  xa is fp32 or bf16; xadd is fp32.
// Optionally emit fp32 and/or bf16 outputs. 128 threads / row.
// ---------------------------------------------------------------------------
template<bool A_BF16, bool EMIT_F32, bool EMIT_BF16>
__global__ __launch_bounds__(128)
void add_ln(const void* __restrict__ xa_, const float* __restrict__ xadd,
            const float* __restrict__ g, const float* __restrict__ be,
            float* __restrict__ y, bf16_t* __restrict__ yb)
{
  const long row = blockIdx.x;
  const int c = threadIdx.x * 4;
  float av[4];
  if constexpr (A_BF16) {
    const bf16_t* xa = (const bf16_t*)xa_;
    bf16x4 a = *(const bf16x4*)&xa[row * 512 + c];
#pragma unroll
    for (int j = 0; j < 4; j++) av[j] = (float)a[j];
  } else {
    const float* xa = (const float*)xa_;
    const float4 a = *(const float4*)&xa[row * 512 + c];
    av[0] = a.x; av[1] = a.y; av[2] = a.z; av[3] = a.w;
  }
  const float4 bb = *(const float4*)&xadd[row * 512 + c];
  float vv[4] = { av[0] + bb.x, av[1] + bb.y, av[2] + bb.z, av[3] + bb.w };
  float s = 0.f, s2 = 0.f;
#pragma unroll
  for (int j = 0; j < 4; j++) { s += vv[j]; s2 += vv[j] * vv[j]; }
  for (int o = 32; o; o >>= 1) { s += __shfl_xor(s, o); s2 += __shfl_xor(s2, o); }
  __shared__ float r0[2], r1[2];
  const int w = threadIdx.x >> 6;
  if ((threadIdx.x & 63) == 0) { r0[w] = s; r1[w] = s2; }
  __syncthreads();
  s = r0[0] + r0[1]; s2 = r1[0] + r1[1];
  const float mu = s * (1.f / 512.f);
  const float var = s2 * (1.f / 512.f) - mu * mu;
  const float rstd = rsqrtf(var + 1e-5f);
  const float4 gg = *(const float4*)&g[c];
  const float4 bev = *(const float4*)&be[c];
  float o0 = (vv[0] - mu) * rstd * gg.x + bev.x;
  float o1 = (vv[1] - mu) * rstd * gg.y + bev.y;
  float o2 = (vv[2] - mu) * rstd * gg.z + bev.z;
  float o3 = (vv[3] - mu) * rstd * gg.w + bev.w;
  if constexpr (EMIT_F32) {
    float4 yo = { o0, o1, o2, o3 };
    *(float4*)&y[row * 512 + c] = yo;
  }
  if constexpr (EMIT_BF16) {
    bf16x4 ob = { (bf16_t)o0, (bf16_t)o1, (bf16_t)o2, (bf16_t)o3 };
    *(bf16x4*)&yb[row * 512 + c] = ob;
  }
}

// ---------------------------------------------------------------------------
extern "C" void kernel_launch(void* const* d_in, const int* in_sizes, int n_in,
                              void* d_out, int out_size, void* d_ws, size_t ws_size,
                              hipStream_t stream)
{
  const float* x   = (const float*)d_in[0];
  const float* wq  = (const float*)d_in[1];
  const float* bq  = (const float*)d_in[2];
  const float* wk  = (const float*)d_in[3];
  const float* bk  = (const float*)d_in[4];
  const float* wv  = (const float*)d_in[5];
  const float* bv  = (const float*)d_in[6];
  const float* wp  = (const float*)d_in[7];
  const float* bp  = (const float*)d_in[8];
  const float* w1  = (const float*)d_in[9];
  const float* b1  = (const float*)d_in[10];
  const float* w2  = (const float*)d_in[11];
  const float* b2  = (const float*)d_in[12];
  const float* g1  = (const float*)d_in[13];
  const float* be1 = (const float*)d_in[14];
  const float* g2  = (const float*)d_in[15];
  const float* be2 = (const float*)d_in[16];

  const long S = 16L * 2048 * 512;   // tokens*D = 16,777,216
  const long Mi = 1L << 20;

  // Workspace layout (248 MiB total). d_out (64 MiB fp32) doubles as scratch
  // for attp (proj output) and ff (FF2 output).
  const size_t NEED = (size_t)248 * Mi;
  if (ws_size < NEED) return;   // diagnostic guard: stub-like failure => ws too small

  char* wsp = (char*)d_ws;
  bf16_t* wqT = (bf16_t*)(wsp + 0);            // 0.5 MiB each
  bf16_t* wkT = wqT + 512 * 512;
  bf16_t* wvT = wkT + 512 * 512;
  bf16_t* wpT = wvT + 512 * 512;
  bf16_t* w1T = wpT + 512 * 512;               // [2048][512], 2 MiB
  bf16_t* w2T = w1T + 512L * 2048;             // [512][2048], 2 MiB
  bf16_t* xb  = (bf16_t*)(wsp +   8 * Mi);     // 32 MiB
  bf16_t* qb  = (bf16_t*)(wsp +  40 * Mi);     // 32
  bf16_t* kb  = (bf16_t*)(wsp +  72 * Mi);     // 32 (reused as FFN h chunk)
  bf16_t* vb  = (bf16_t*)(wsp + 104 * Mi);     // 32
  bf16_t* vT  = (bf16_t*)(wsp + 136 * Mi);     // 32
  bf16_t* ob  = (bf16_t*)(wsp + 168 * Mi);     // 32
  bf16_t* x1b = (bf16_t*)(wsp + 200 * Mi);     // 32
  bf16_t* E   = (bf16_t*)(wsp + 232 * Mi);     // 16 (2-batch score chunk)
  bf16_t* h   = kb;                            // [8192][2048] per FFN chunk
  float*  attp = (float*)d_out;                // [32768][512] fp32 scratch
  float*  ff   = (float*)d_out;

  // 1. cast x -> bf16
  cast_to_bf16<<<dim3((unsigned)(S / 4 / 256)), 256, 0, stream>>>(x, xb, S);

  // 2. weight transposes (to B^T layout, bf16)
  transpose_cast<float><<<dim3(16, 16, 1), 256, 0, stream>>>(wq, wqT, 512, 512, 0, 0);
  transpose_cast<float><<<dim3(16, 16, 1), 256, 0, stream>>>(wk, wkT, 512, 512, 0, 0);
  transpose_cast<float><<<dim3(16, 16, 1), 256, 0, stream>>>(wv, wvT, 512, 512, 0, 0);
  transpose_cast<float><<<dim3(16, 16, 1), 256, 0, stream>>>(wp, wpT, 512, 512, 0, 0);
  transpose_cast<float><<<dim3(64, 16, 1), 256, 0, stream>>>(w1, w1T, 512, 2048, 0, 0);
  transpose_cast<float><<<dim3(16, 64, 1), 256, 0, stream>>>(w2, w2T, 2048, 512, 0, 0);

  // 3. QKV GEMMs (M=32768, N=512, K=512)
  const dim3 gQKV(4, 256, 1);
  gemm_bt<2, true><<<gQKV, 256, 0, stream>>>(xb, wqT, bq, qb, 32768, 512, 512,
                                             0, 0, 0, 0.04419417382f); // q / sqrt(512)
  gemm_bt<1, true><<<gQKV, 256, 0, stream>>>(xb, wkT, bk, kb, 32768, 512, 512, 0, 0, 0, 0.f);
  gemm_bt<1, true><<<gQKV, 256, 0, stream>>>(xb, wvT, bv, vb, 32768, 512, 512, 0, 0, 0, 0.f);

  // 4. V transpose per batch: [2048][512] -> [512][2048]
  transpose_cast<bf16_t><<<dim3(16, 64, 16), 256, 0, stream>>>(
      vb, vT, 2048, 512, 2048L * 512, 512L * 2048);

  // 5. attention in chunks of 2 batches (E chunk = 16 MiB)
  for (int c = 0; c < 8; c++) {
    const long boff = (long)c * 2 * 2048 * 512;   // token offset * D
    // E = (q/tau) k^T   (M=N=2048, K=512, z=2)
    gemm_bt<1, false><<<dim3(16, 16, 2), 256, 0, stream>>>(
        qb + boff, kb + boff, nullptr, E, 2048, 2048, 512,
        2048L * 512, 2048L * 512, 2048L * 2048, 0.f);
    // softmax rows (2 batches * 2048 rows)
    softmax2048<<<dim3(4096), 256, 0, stream>>>(E);
    // out = P V  (M=2048, N=512, K=2048, z=2)
    gemm_bt<1, false><<<dim3(4, 16, 2), 256, 0, stream>>>(
        E, vT + (long)c * 2 * 512 * 2048, nullptr, ob + boff, 2048, 512, 2048,
        2048L * 2048, 512L * 2048, 2048L * 512, 0.f);
  }

  // 6. proj -> attp (= d_out, fp32)
  gemm_bt<0, true><<<dim3(4, 256, 1), 256, 0, stream>>>(
      ob, wpT, bp, attp, 32768, 512, 512, 0, 0, 0, 0.f);

  // 7. x1b = bf16( LN(x + attp) )
  add_ln<false, false, true><<<dim3(32768), 128, 0, stream>>>(
      x, attp, g1, be1, nullptr, x1b);

  // 8. FFN in 4 row-chunks of 8192 (h chunk reuses kb, 32 MiB)
  for (int c = 0; c < 4; c++) {
    const long roff = (long)c * 8192;
    // FF1: h = gelu(x1 w1 + b1)  (M=8192, N=2048, K=512)
    gemm_bt<3, true><<<dim3(16, 64, 1), 256, 0, stream>>>(
        x1b + roff * 512, w1T, b1, h, 8192, 2048, 512, 0, 0, 0, 0.f);
    // FF2: ff = h w2 + b2 -> d_out rows (fp32)  (M=8192, N=512, K=2048)
    gemm_bt<0, true><<<dim3(4, 64, 1), 256, 0, stream>>>(
        h, w2T, b2, ff + roff * 512, 8192, 512, 2048, 0, 0, 0, 0.f);
  }

  // 9. out = LN(x1 + ff), in place on d_out
  add_ln<true, true, false><<<dim3(32768), 128, 0, stream>>>(
      x1b, ff, g2, be2, (float*)d_out, nullptr);
}

// Round 3
// 1131.401 us; speedup vs baseline: 1.0678x; 1.0678x over previous
//
#include <hip/hip_runtime.h>
#include <cmath>

typedef __bf16 bf16_t;
typedef __bf16 bf16x8 __attribute__((ext_vector_type(8)));
typedef __bf16 bf16x4 __attribute__((ext_vector_type(4)));
typedef float f32x4 __attribute__((ext_vector_type(4)));

#define DEV_INLINE __device__ __forceinline__

DEV_INLINE void gload_lds16(const void* g, void* l) {
  __builtin_amdgcn_global_load_lds(
      (const __attribute__((address_space(1))) void*)g,
      (__attribute__((address_space(3))) void*)l, 16, 0, 0);
}

// ---------------------------------------------------------------------------
// GEMM: C = A[M][K] * B^T  (B stored [N][K]) + bias, with fused epilogue.
// EPI: 0 = fp32 out, 1 = bf16 out, 2 = bf16 out *scale, 3 = bf16 gelu(out)
// 128x128 tile, BK=32, 256 threads = 4 waves (2x2), wave tile 64x64 (4x4 frags)
// 2-phase schedule: prefetch next k-tile into the other LDS buffer BEFORE the
// current tile's ds_read+MFMA; single __syncthreads at end of iteration so the
// compiler's vmcnt(0) drain lands after the compute phase (T3 minimum recipe).
// ---------------------------------------------------------------------------
template<int EPI, bool HAS_BIAS>
__global__ __launch_bounds__(256)
void gemm_bt(const bf16_t* __restrict__ A, const bf16_t* __restrict__ B,
             const float* __restrict__ bias, void* __restrict__ C,
             int M, int N, int K,
             long sA, long sB, long sC, float scale)
{
  __shared__ alignas(16) bf16_t As[2][128 * 32];
  __shared__ alignas(16) bf16_t Bs[2][128 * 32];
  const int b = blockIdx.z;
  A += (long)b * sA;
  B += (long)b * sB;
  const int t  = threadIdx.x;
  const int l  = t & 63;
  const int w  = t >> 6;
  const int wr = (w >> 1) * 64;   // wave row offset in tile
  const int wc = (w & 1) * 64;    // wave col offset in tile
  const int m0 = blockIdx.y * 128;
  const int n0 = blockIdx.x * 128;

  // staging: thread t loads 16B chunks; LDS dest is wave-uniform base + lane*16.
  const int srow = t >> 2;
  const int scol = (t & 3) * 8;
  const bf16_t* ga0 = A + (long)(m0 + srow) * K + scol;
  const bf16_t* ga1 = A + (long)(m0 + 64 + srow) * K + scol;
  const bf16_t* gb0 = B + (long)(n0 + srow) * K + scol;
  const bf16_t* gb1 = B + (long)(n0 + 64 + srow) * K + scol;

  f32x4 acc[4][4] = {};

  const int fr = l & 15;         // fragment row (A) / col (B) within 16
  const int kk = (l >> 4) * 8;   // k offset within 32

  // prologue: stage k-tile 0 into buffer 0
  gload_lds16(ga0, &As[0][t * 8]);
  gload_lds16(ga1, &As[0][2048 + t * 8]);
  gload_lds16(gb0, &Bs[0][t * 8]);
  gload_lds16(gb1, &Bs[0][2048 + t * 8]);
  __syncthreads();

  int cur = 0;
  for (int k0 = 0; k0 < K; k0 += 32) {
    const int nxt = k0 + 32;
    if (nxt < K) {            // issue next tile's loads (overlap with compute)
      gload_lds16(ga0 + nxt, &As[cur ^ 1][t * 8]);
      gload_lds16(ga1 + nxt, &As[cur ^ 1][2048 + t * 8]);
      gload_lds16(gb0 + nxt, &Bs[cur ^ 1][t * 8]);
      gload_lds16(gb1 + nxt, &Bs[cur ^ 1][2048 + t * 8]);
    }
    bf16x8 af[4], bfr[4];
#pragma unroll
    for (int mi = 0; mi < 4; mi++)
      af[mi] = *(const bf16x8*)&As[cur][(wr + mi * 16 + fr) * 32 + kk];
#pragma unroll
    for (int ni = 0; ni < 4; ni++)
      bfr[ni] = *(const bf16x8*)&Bs[cur][(wc + ni * 16 + fr) * 32 + kk];
#pragma unroll
    for (int mi = 0; mi < 4; mi++)
#pragma unroll
      for (int ni = 0; ni < 4; ni++)
        acc[mi][ni] = __builtin_amdgcn_mfma_f32_16x16x32_bf16(
            af[mi], bfr[ni], acc[mi][ni], 0, 0, 0);
    __syncthreads();          // drains prefetch vmem + lgkm; next buffer ready
    cur ^= 1;
  }

  // C/D layout: col = lane&15, row = 4*(lane>>4) + reg
  const long cb = (long)b * sC;
#pragma unroll
  for (int mi = 0; mi < 4; mi++) {
#pragma unroll
    for (int ni = 0; ni < 4; ni++) {
      const int c = n0 + wc + ni * 16 + fr;
      float bias_v = 0.f;
      if constexpr (HAS_BIAS) bias_v = bias[c];
#pragma unroll
      for (int r = 0; r < 4; r++) {
        const int row = m0 + wr + mi * 16 + (l >> 4) * 4 + r;
        float v = acc[mi][ni][r] + bias_v;
        if constexpr (EPI == 2) v *= scale;
        if constexpr (EPI == 3) v = 0.5f * v * (1.f + erff(v * 0.70710678118f));
        const long idx = cb + (long)row * N + c;
        if constexpr (EPI == 0) ((float*)C)[idx] = v;
        else                    ((bf16_t*)C)[idx] = (bf16_t)v;
      }
    }
  }
}

// ---------------------------------------------------------------------------
// Transpose + cast to bf16: in [R][Cc] (SrcT) -> out [Cc][R] (bf16), batched.
// ---------------------------------------------------------------------------
template<typename SrcT>
__global__ __launch_bounds__(256)
void transpose_cast(const SrcT* __restrict__ in, bf16_t* __restrict__ out,
                    int R, int Cc, long sIn, long sOut)
{
  __shared__ float tile[32][33];
  const int b = blockIdx.z;
  in  += (long)b * sIn;
  out += (long)b * sOut;
  const int c0 = blockIdx.x * 32;
  const int r0 = blockIdx.y * 32;
  const int tx = threadIdx.x & 31;
  const int ty = threadIdx.x >> 5;  // 0..7
#pragma unroll
  for (int i = 0; i < 32; i += 8)
    tile[ty + i][tx] = (float)in[(long)(r0 + ty + i) * Cc + (c0 + tx)];
  __syncthreads();
#pragma unroll
  for (int i = 0; i < 32; i += 8)
    out[(long)(c0 + ty + i) * R + (r0 + tx)] = (bf16_t)tile[tx][ty + i];
}

__global__ __launch_bounds__(256)
void cast_to_bf16(const float* __restrict__ in, bf16_t* __restrict__ out, long n)
{
  const long i = ((long)blockIdx.x * 256 + threadIdx.x) * 4;
  if (i >= n) return;
  const float4 v = *(const float4*)&in[i];
  bf16x4 o = { (bf16_t)v.x, (bf16_t)v.y, (bf16_t)v.z, (bf16_t)v.w };
  *(bf16x4*)&out[i] = o;
}

// ---------------------------------------------------------------------------
// Row softmax over 2048 bf16 elements, in place. One 256-thread block per row.
// ---------------------------------------------------------------------------
__global__ __launch_bounds__(256)
void softmax2048(bf16_t* __restrict__ E)
{
  const long row = blockIdx.x;
  bf16_t* p = E + row * 2048;
  const int t = threadIdx.x;
  bf16x8 xv = *(const bf16x8*)&p[t * 8];
  float v[8];
#pragma unroll
  for (int j = 0; j < 8; j++) v[j] = (float)xv[j];
  float m = v[0];
#pragma unroll
  for (int j = 1; j < 8; j++) m = fmaxf(m, v[j]);
  for (int o = 32; o; o >>= 1) m = fmaxf(m, __shfl_xor(m, o));
  __shared__ float redm[4];
  __shared__ float reds[4];
  if ((t & 63) == 0) redm[t >> 6] = m;
  __syncthreads();
  m = fmaxf(fmaxf(redm[0], redm[1]), fmaxf(redm[2], redm[3]));
  float s = 0.f;
#pragma unroll
  for (int j = 0; j < 8; j++) { v[j] = __expf(v[j] - m); s += v[j]; }
  for (int o = 32; o; o >>= 1) s += __shfl_xor(s, o);
  if ((t & 63) == 0) reds[t >> 6] = s;
  __syncthreads();
  s = reds[0] + reds[1] + reds[2] + reds[3];
  const float inv = 1.f / s;
  bf16x8 ov;
#pragma unroll
  for (int j = 0; j < 8; j++) ov[j] = (bf16_t)(v[j] * inv);
  *(bf16x8*)&p[t * 8] = ov;
}

// ---------------------------------------------------------------------------
// Fused residual add + LayerNorm over rows of 512.
// y = LN(xa + xadd) * g + be.  xa is fp32 or bf16; xadd is fp32.
// Optionally emit fp32 and/or bf16 outputs. 128 threads / row.
// ---------------------------------------------------------------------------
template<bool A_BF16, bool EMIT_F32, bool EMIT_BF16>
__global__ __launch_bounds__(128)
void add_ln(const void* __restrict__ xa_, const float* __restrict__ xadd,
            const float* __restrict__ g, const float* __restrict__ be,
            float* __restrict__ y, bf16_t* __restrict__ yb)
{
  const long row = blockIdx.x;
  const int c = threadIdx.x * 4;
  float av[4];
  if constexpr (A_BF16) {
    const bf16_t* xa = (const bf16_t*)xa_;
    bf16x4 a = *(const bf16x4*)&xa[row * 512 + c];
#pragma unroll
    for (int j = 0; j < 4; j++) av[j] = (float)a[j];
  } else {
    const float* xa = (const float*)xa_;
    const float4 a = *(const float4*)&xa[row * 512 + c];
    av[0] = a.x; av[1] = a.y; av[2] = a.z; av[3] = a.w;
  }
  const float4 bb = *(const float4*)&xadd[row * 512 + c];
  float vv[4] = { av[0] + bb.x, av[1] + bb.y, av[2] + bb.z, av[3] + bb.w };
  float s = 0.f, s2 = 0.f;
#pragma unroll
  for (int j = 0; j < 4; j++) { s += vv[j]; s2 += vv[j] * vv[j]; }
  for (int o = 32; o; o >>= 1) { s += __shfl_xor(s, o); s2 += __shfl_xor(s2, o); }
  __shared__ float r0[2], r1[2];
  const int w = threadIdx.x >> 6;
  if ((threadIdx.x & 63) == 0) { r0[w] = s; r1[w] = s2; }
  __syncthreads();
  s = r0[0] + r0[1]; s2 = r1[0] + r1[1];
  const float mu = s * (1.f / 512.f);
  const float var = s2 * (1.f / 512.f) - mu * mu;
  const float rstd = rsqrtf(var + 1e-5f);
  const float4 gg = *(const float4*)&g[c];
  const float4 bev = *(const float4*)&be[c];
  float o0 = (vv[0] - mu) * rstd * gg.x + bev.x;
  float o1 = (vv[1] - mu) * rstd * gg.y + bev.y;
  float o2 = (vv[2] - mu) * rstd * gg.z + bev.z;
  float o3 = (vv[3] - mu) * rstd * gg.w + bev.w;
  if constexpr (EMIT_F32) {
    float4 yo = { o0, o1, o2, o3 };
    *(float4*)&y[row * 512 + c] = yo;
  }
  if constexpr (EMIT_BF16) {
    bf16x4 ob = { (bf16_t)o0, (bf16_t)o1, (bf16_t)o2, (bf16_t)o3 };
    *(bf16x4*)&yb[row * 512 + c] = ob;
  }
}

// ---------------------------------------------------------------------------
extern "C" void kernel_launch(void* const* d_in, const int* in_sizes, int n_in,
                              void* d_out, int out_size, void* d_ws, size_t ws_size,
                              hipStream_t stream)
{
  const float* x   = (const float*)d_in[0];
  const float* wq  = (const float*)d_in[1];
  const float* bq  = (const float*)d_in[2];
  const float* wk  = (const float*)d_in[3];
  const float* bk  = (const float*)d_in[4];
  const float* wv  = (const float*)d_in[5];
  const float* bv  = (const float*)d_in[6];
  const float* wp  = (const float*)d_in[7];
  const float* bp  = (const float*)d_in[8];
  const float* w1  = (const float*)d_in[9];
  const float* b1  = (const float*)d_in[10];
  const float* w2  = (const float*)d_in[11];
  const float* b2  = (const float*)d_in[12];
  const float* g1  = (const float*)d_in[13];
  const float* be1 = (const float*)d_in[14];
  const float* g2  = (const float*)d_in[15];
  const float* be2 = (const float*)d_in[16];

  const long S = 16L * 2048 * 512;   // tokens*D = 16,777,216
  const long Mi = 1L << 20;

  // Workspace layout (248 MiB total). d_out (64 MiB fp32) doubles as scratch
  // for attp (proj output) and ff (FF2 output).
  const size_t NEED = (size_t)248 * Mi;
  if (ws_size < NEED) return;   // diagnostic guard: stub-like failure => ws too small

  char* wsp = (char*)d_ws;
  bf16_t* wqT = (bf16_t*)(wsp + 0);            // 0.5 MiB each
  bf16_t* wkT = wqT + 512 * 512;
  bf16_t* wvT = wkT + 512 * 512;
  bf16_t* wpT = wvT + 512 * 512;
  bf16_t* w1T = wpT + 512 * 512;               // [2048][512], 2 MiB
  bf16_t* w2T = w1T + 512L * 2048;             // [512][2048], 2 MiB
  bf16_t* xb  = (bf16_t*)(wsp +   8 * Mi);     // 32 MiB
  bf16_t* qb  = (bf16_t*)(wsp +  40 * Mi);     // 32
  bf16_t* kb  = (bf16_t*)(wsp +  72 * Mi);     // 32 (reused as FFN h chunk)
  bf16_t* vb  = (bf16_t*)(wsp + 104 * Mi);     // 32
  bf16_t* vT  = (bf16_t*)(wsp + 136 * Mi);     // 32
  bf16_t* ob  = (bf16_t*)(wsp + 168 * Mi);     // 32
  bf16_t* x1b = (bf16_t*)(wsp + 200 * Mi);     // 32
  bf16_t* E   = (bf16_t*)(wsp + 232 * Mi);     // 16 (2-batch score chunk)
  bf16_t* h   = kb;                            // [8192][2048] per FFN chunk
  float*  attp = (float*)d_out;                // [32768][512] fp32 scratch
  float*  ff   = (float*)d_out;

  // 1. cast x -> bf16
  cast_to_bf16<<<dim3((unsigned)(S / 4 / 256)), 256, 0, stream>>>(x, xb, S);

  // 2. weight transposes (to B^T layout, bf16)
  transpose_cast<float><<<dim3(16, 16, 1), 256, 0, stream>>>(wq, wqT, 512, 512, 0, 0);
  transpose_cast<float><<<dim3(16, 16, 1), 256, 0, stream>>>(wk, wkT, 512, 512, 0, 0);
  transpose_cast<float><<<dim3(16, 16, 1), 256, 0, stream>>>(wv, wvT, 512, 512, 0, 0);
  transpose_cast<float><<<dim3(16, 16, 1), 256, 0, stream>>>(wp, wpT, 512, 512, 0, 0);
  transpose_cast<float><<<dim3(64, 16, 1), 256, 0, stream>>>(w1, w1T, 512, 2048, 0, 0);
  transpose_cast<float><<<dim3(16, 64, 1), 256, 0, stream>>>(w2, w2T, 2048, 512, 0, 0);

  // 3. QKV GEMMs (M=32768, N=512, K=512)
  const dim3 gQKV(4, 256, 1);
  gemm_bt<2, true><<<gQKV, 256, 0, stream>>>(xb, wqT, bq, qb, 32768, 512, 512,
                                             0, 0, 0, 0.04419417382f); // q / sqrt(512)
  gemm_bt<1, true><<<gQKV, 256, 0, stream>>>(xb, wkT, bk, kb, 32768, 512, 512, 0, 0, 0, 0.f);
  gemm_bt<1, true><<<gQKV, 256, 0, stream>>>(xb, wvT, bv, vb, 32768, 512, 512, 0, 0, 0, 0.f);

  // 4. V transpose per batch: [2048][512] -> [512][2048]
  transpose_cast<bf16_t><<<dim3(16, 64, 16), 256, 0, stream>>>(
      vb, vT, 2048, 512, 2048L * 512, 512L * 2048);

  // 5. attention in chunks of 2 batches (E chunk = 16 MiB)
  for (int c = 0; c < 8; c++) {
    const long boff = (long)c * 2 * 2048 * 512;   // token offset * D
    // E = (q/tau) k^T   (M=N=2048, K=512, z=2)
    gemm_bt<1, false><<<dim3(16, 16, 2), 256, 0, stream>>>(
        qb + boff, kb + boff, nullptr, E, 2048, 2048, 512,
        2048L * 512, 2048L * 512, 2048L * 2048, 0.f);
    // softmax rows (2 batches * 2048 rows)
    softmax2048<<<dim3(4096), 256, 0, stream>>>(E);
    // out = P V  (M=2048, N=512, K=2048, z=2)
    gemm_bt<1, false><<<dim3(4, 16, 2), 256, 0, stream>>>(
        E, vT + (long)c * 2 * 512 * 2048, nullptr, ob + boff, 2048, 512, 2048,
        2048L * 2048, 512L * 2048, 2048L * 512, 0.f);
  }

  // 6. proj -> attp (= d_out, fp32)
  gemm_bt<0, true><<<dim3(4, 256, 1), 256, 0, stream>>>(
      ob, wpT, bp, attp, 32768, 512, 512, 0, 0, 0, 0.f);

  // 7. x1b = bf16( LN(x + attp) )
  add_ln<false, false, true><<<dim3(32768), 128, 0, stream>>>(
      x, attp, g1, be1, nullptr, x1b);

  // 8. FFN in 4 row-chunks of 8192 (h chunk reuses kb, 32 MiB)
  for (int c = 0; c < 4; c++) {
    const long roff = (long)c * 8192;
    // FF1: h = gelu(x1 w1 + b1)  (M=8192, N=2048, K=512)
    gemm_bt<3, true><<<dim3(16, 64, 1), 256, 0, stream>>>(
        x1b + roff * 512, w1T, b1, h, 8192, 2048, 512, 0, 0, 0, 0.f);
    // FF2: ff = h w2 + b2 -> d_out rows (fp32)  (M=8192, N=512, K=2048)
    gemm_bt<0, true><<<dim3(4, 64, 1), 256, 0, stream>>>(
        h, w2T, b2, ff + roff * 512, 8192, 512, 2048, 0, 0, 0, 0.f);
  }

  // 9. out = LN(x1 + ff), in place on d_out
  add_ln<true, true, false><<<dim3(32768), 128, 0, stream>>>(
      x1b, ff, g2, be2, (float*)d_out, nullptr);
}

// Round 4
// 703.950 us; speedup vs baseline: 1.7162x; 1.6072x over previous
//
#include <hip/hip_runtime.h>
#include <cmath>

typedef __bf16 bf16_t;
typedef __bf16 bf16x8 __attribute__((ext_vector_type(8)));
typedef __bf16 bf16x4 __attribute__((ext_vector_type(4)));
typedef float f32x4 __attribute__((ext_vector_type(4)));

#define DEV_INLINE __device__ __forceinline__

DEV_INLINE void gload_lds16(const void* g, void* l) {
  __builtin_amdgcn_global_load_lds(
      (const __attribute__((address_space(1))) void*)g,
      (__attribute__((address_space(3))) void*)l, 16, 0, 0);
}

// ---------------------------------------------------------------------------
// GEMM: C = A[M][.lda] * B^T (B stored [N][.ldb]) + bias, fused epilogue.
// EPI: 0 = fp32 out, 1 = bf16 out, 2 = bf16 out *scale (no bias), 3 = bf16
//      gelu(out), 5 = merged-QKV split: cols<1024 -> bf16 C[row][c] (ldc),
//      cols>=1024 -> V written TRANSPOSED per batch into vTaux[b][c-1024][n].
// 128x128 tile, BK=32, 256 threads = 4 waves (2x2), wave tile 64x64.
// 2-phase LDS double-buffer (prefetch next k-tile before compute).
// ---------------------------------------------------------------------------
template<int EPI, bool HAS_BIAS>
__global__ __launch_bounds__(256)
void gemm_bt(const bf16_t* __restrict__ A, const bf16_t* __restrict__ B,
             const float* __restrict__ bias, void* __restrict__ C,
             bf16_t* __restrict__ vTaux,
             int M, int N, int K, int lda, int ldb, int ldc,
             long sA, long sB, long sC, float scale)
{
  __shared__ alignas(16) bf16_t As[2][128 * 32];
  __shared__ alignas(16) bf16_t Bs[2][128 * 32];
  const int b = blockIdx.z;
  A += (long)b * sA;
  B += (long)b * sB;
  const int t  = threadIdx.x;
  const int l  = t & 63;
  const int w  = t >> 6;
  const int wr = (w >> 1) * 64;
  const int wc = (w & 1) * 64;
  const int m0 = blockIdx.y * 128;
  const int n0 = blockIdx.x * 128;

  const int srow = t >> 2;
  const int scol = (t & 3) * 8;
  const bf16_t* ga0 = A + (long)(m0 + srow) * lda + scol;
  const bf16_t* ga1 = A + (long)(m0 + 64 + srow) * lda + scol;
  const bf16_t* gb0 = B + (long)(n0 + srow) * ldb + scol;
  const bf16_t* gb1 = B + (long)(n0 + 64 + srow) * ldb + scol;

  f32x4 acc[4][4] = {};

  const int fr = l & 15;
  const int kk = (l >> 4) * 8;

  gload_lds16(ga0, &As[0][t * 8]);
  gload_lds16(ga1, &As[0][2048 + t * 8]);
  gload_lds16(gb0, &Bs[0][t * 8]);
  gload_lds16(gb1, &Bs[0][2048 + t * 8]);
  __syncthreads();

  int cur = 0;
  for (int k0 = 0; k0 < K; k0 += 32) {
    const int nxt = k0 + 32;
    if (nxt < K) {
      gload_lds16(ga0 + nxt, &As[cur ^ 1][t * 8]);
      gload_lds16(ga1 + nxt, &As[cur ^ 1][2048 + t * 8]);
      gload_lds16(gb0 + nxt, &Bs[cur ^ 1][t * 8]);
      gload_lds16(gb1 + nxt, &Bs[cur ^ 1][2048 + t * 8]);
    }
    bf16x8 af[4], bfr[4];
#pragma unroll
    for (int mi = 0; mi < 4; mi++)
      af[mi] = *(const bf16x8*)&As[cur][(wr + mi * 16 + fr) * 32 + kk];
#pragma unroll
    for (int ni = 0; ni < 4; ni++)
      bfr[ni] = *(const bf16x8*)&Bs[cur][(wc + ni * 16 + fr) * 32 + kk];
#pragma unroll
    for (int mi = 0; mi < 4; mi++)
#pragma unroll
      for (int ni = 0; ni < 4; ni++)
        acc[mi][ni] = __builtin_amdgcn_mfma_f32_16x16x32_bf16(
            af[mi], bfr[ni], acc[mi][ni], 0, 0, 0);
    __syncthreads();
    cur ^= 1;
  }

  // C/D layout: col = lane&15, row = 4*(lane>>4) + reg
  const long cb = (long)b * sC;
  const int rbase = m0 + wr + (l >> 4) * 4;   // +mi*16 per fragment row
#pragma unroll
  for (int mi = 0; mi < 4; mi++) {
    const int row0 = rbase + mi * 16;
#pragma unroll
    for (int ni = 0; ni < 4; ni++) {
      const int c = n0 + wc + ni * 16 + fr;
      float bias_v = 0.f;
      if constexpr (HAS_BIAS) bias_v = bias[c];
      float vals[4];
#pragma unroll
      for (int r = 0; r < 4; r++) {
        float v = acc[mi][ni][r] + bias_v;
        if constexpr (EPI == 2) v *= scale;
        if constexpr (EPI == 3) v = 0.5f * v * (1.f + erff(v * 0.70710678118f));
        vals[r] = v;
      }
      if constexpr (EPI == 5) {
        if (c < 1024) {           // block-uniform branch (n0 128-aligned)
#pragma unroll
          for (int r = 0; r < 4; r++)
            ((bf16_t*)C)[(long)(row0 + r) * ldc + c] = (bf16_t)vals[r];
        } else {
          const int bb = row0 >> 11;        // batch
          const int n  = row0 & 2047;       // token within batch (mult of 4)
          bf16x4 pk = { (bf16_t)vals[0], (bf16_t)vals[1],
                        (bf16_t)vals[2], (bf16_t)vals[3] };
          *(bf16x4*)&vTaux[(long)bb * (512 * 2048) + (long)(c - 1024) * 2048 + n] = pk;
        }
      } else {
#pragma unroll
        for (int r = 0; r < 4; r++) {
          const long idx = cb + (long)(row0 + r) * ldc + c;
          if constexpr (EPI == 0) ((float*)C)[idx] = vals[r];
          else                    ((bf16_t*)C)[idx] = (bf16_t)vals[r];
        }
      }
    }
  }
}

// ---------------------------------------------------------------------------
// Transpose + cast to bf16: in [R][Cc] (fp32) -> out [Cc][R] (bf16).
// ---------------------------------------------------------------------------
__global__ __launch_bounds__(256)
void transpose_cast(const float* __restrict__ in, bf16_t* __restrict__ out,
                    int R, int Cc)
{
  __shared__ float tile[32][33];
  const int c0 = blockIdx.x * 32;
  const int r0 = blockIdx.y * 32;
  const int tx = threadIdx.x & 31;
  const int ty = threadIdx.x >> 5;
#pragma unroll
  for (int i = 0; i < 32; i += 8)
    tile[ty + i][tx] = in[(long)(r0 + ty + i) * Cc + (c0 + tx)];
  __syncthreads();
#pragma unroll
  for (int i = 0; i < 32; i += 8)
    out[(long)(c0 + ty + i) * R + (r0 + tx)] = (bf16_t)tile[tx][ty + i];
}

__global__ __launch_bounds__(256)
void cast_to_bf16(const float* __restrict__ in, bf16_t* __restrict__ out, long n)
{
  const long i = ((long)blockIdx.x * 256 + threadIdx.x) * 4;
  if (i >= n) return;
  const float4 v = *(const float4*)&in[i];
  bf16x4 o = { (bf16_t)v.x, (bf16_t)v.y, (bf16_t)v.z, (bf16_t)v.w };
  *(bf16x4*)&out[i] = o;
}

// concat bq|bk|bv -> bqkv[1536]
__global__ __launch_bounds__(256)
void concat_bias(const float* __restrict__ a, const float* __restrict__ b,
                 const float* __restrict__ c, float* __restrict__ o)
{
  const int i = blockIdx.x * 256 + threadIdx.x;
  if (i < 512) o[i] = a[i];
  else if (i < 1024) o[i] = b[i - 512];
  else if (i < 1536) o[i] = c[i - 1024];
}

// ---------------------------------------------------------------------------
// Row softmax over 2048 bf16 elements, in place. One 256-thread block per row.
// ---------------------------------------------------------------------------
__global__ __launch_bounds__(256)
void softmax2048(bf16_t* __restrict__ E)
{
  const long row = blockIdx.x;
  bf16_t* p = E + row * 2048;
  const int t = threadIdx.x;
  bf16x8 xv = *(const bf16x8*)&p[t * 8];
  float v[8];
#pragma unroll
  for (int j = 0; j < 8; j++) v[j] = (float)xv[j];
  float m = v[0];
#pragma unroll
  for (int j = 1; j < 8; j++) m = fmaxf(m, v[j]);
  for (int o = 32; o; o >>= 1) m = fmaxf(m, __shfl_xor(m, o));
  __shared__ float redm[4];
  __shared__ float reds[4];
  if ((t & 63) == 0) redm[t >> 6] = m;
  __syncthreads();
  m = fmaxf(fmaxf(redm[0], redm[1]), fmaxf(redm[2], redm[3]));
  float s = 0.f;
#pragma unroll
  for (int j = 0; j < 8; j++) { v[j] = __expf(v[j] - m); s += v[j]; }
  for (int o = 32; o; o >>= 1) s += __shfl_xor(s, o);
  if ((t & 63) == 0) reds[t >> 6] = s;
  __syncthreads();
  s = reds[0] + reds[1] + reds[2] + reds[3];
  const float inv = 1.f / s;
  bf16x8 ov;
#pragma unroll
  for (int j = 0; j < 8; j++) ov[j] = (bf16_t)(v[j] * inv);
  *(bf16x8*)&p[t * 8] = ov;
}

// ---------------------------------------------------------------------------
// Fused residual add + LayerNorm over rows of 512.
// ---------------------------------------------------------------------------
template<bool A_BF16, bool EMIT_F32, bool EMIT_BF16>
__global__ __launch_bounds__(128)
void add_ln(const void* __restrict__ xa_, const float* __restrict__ xadd,
            const float* __restrict__ g, const float* __restrict__ be,
            float* __restrict__ y, bf16_t* __restrict__ yb)
{
  const long row = blockIdx.x;
  const int c = threadIdx.x * 4;
  float av[4];
  if constexpr (A_BF16) {
    const bf16_t* xa = (const bf16_t*)xa_;
    bf16x4 a = *(const bf16x4*)&xa[row * 512 + c];
#pragma unroll
    for (int j = 0; j < 4; j++) av[j] = (float)a[j];
  } else {
    const float* xa = (const float*)xa_;
    const float4 a = *(const float4*)&xa[row * 512 + c];
    av[0] = a.x; av[1] = a.y; av[2] = a.z; av[3] = a.w;
  }
  const float4 bb = *(const float4*)&xadd[row * 512 + c];
  float vv[4] = { av[0] + bb.x, av[1] + bb.y, av[2] + bb.z, av[3] + bb.w };
  float s = 0.f, s2 = 0.f;
#pragma unroll
  for (int j = 0; j < 4; j++) { s += vv[j]; s2 += vv[j] * vv[j]; }
  for (int o = 32; o; o >>= 1) { s += __shfl_xor(s, o); s2 += __shfl_xor(s2, o); }
  __shared__ float r0[2], r1[2];
  const int w = threadIdx.x >> 6;
  if ((threadIdx.x & 63) == 0) { r0[w] = s; r1[w] = s2; }
  __syncthreads();
  s = r0[0] + r0[1]; s2 = r1[0] + r1[1];
  const float mu = s * (1.f / 512.f);
  const float var = s2 * (1.f / 512.f) - mu * mu;
  const float rstd = rsqrtf(var + 1e-5f);
  const float4 gg = *(const float4*)&g[c];
  const float4 bev = *(const float4*)&be[c];
  float o0 = (vv[0] - mu) * rstd * gg.x + bev.x;
  float o1 = (vv[1] - mu) * rstd * gg.y + bev.y;
  float o2 = (vv[2] - mu) * rstd * gg.z + bev.z;
  float o3 = (vv[3] - mu) * rstd * gg.w + bev.w;
  if constexpr (EMIT_F32) {
    float4 yo = { o0, o1, o2, o3 };
    *(float4*)&y[row * 512 + c] = yo;
  }
  if constexpr (EMIT_BF16) {
    bf16x4 ob = { (bf16_t)o0, (bf16_t)o1, (bf16_t)o2, (bf16_t)o3 };
    *(bf16x4*)&yb[row * 512 + c] = ob;
  }
}

// ---------------------------------------------------------------------------
extern "C" void kernel_launch(void* const* d_in, const int* in_sizes, int n_in,
                              void* d_out, int out_size, void* d_ws, size_t ws_size,
                              hipStream_t stream)
{
  const float* x   = (const float*)d_in[0];
  const float* wq  = (const float*)d_in[1];
  const float* bq  = (const float*)d_in[2];
  const float* wk  = (const float*)d_in[3];
  const float* bk  = (const float*)d_in[4];
  const float* wv  = (const float*)d_in[5];
  const float* bv  = (const float*)d_in[6];
  const float* wp  = (const float*)d_in[7];
  const float* bp  = (const float*)d_in[8];
  const float* w1  = (const float*)d_in[9];
  const float* b1  = (const float*)d_in[10];
  const float* w2  = (const float*)d_in[11];
  const float* b2  = (const float*)d_in[12];
  const float* g1  = (const float*)d_in[13];
  const float* be1 = (const float*)d_in[14];
  const float* g2  = (const float*)d_in[15];
  const float* be2 = (const float*)d_in[16];

  const long S = 16L * 2048 * 512;   // tokens*D
  const long Mi = 1L << 20;

  // Workspace (200 MiB):
  //   0: weights (wqkvT 1.5, wpT 0.5, w1T 2, w2T 2, bqkv) -> 8 MiB region
  //   8: xb 32            (reused as ob after QKV)
  //  40: qkb 64 [32768][1024]  (reused: x1b at 40..72, h spans 72..200)
  // 104: vT 32 [16][512][2048]
  // 136: E  64 (8-batch score chunk; 2 passes)
  const size_t NEED = (size_t)200 * Mi;
  if (ws_size < NEED) return;

  char* wsp = (char*)d_ws;
  bf16_t* wqkvT = (bf16_t*)(wsp + 0);            // [1536][512]
  bf16_t* wpT   = wqkvT + 1536L * 512;           // [512][512]
  bf16_t* w1T   = wpT + 512L * 512;              // [2048][512]
  bf16_t* w2T   = w1T + 2048L * 512;             // [512][2048]
  float*  bqkv  = (float*)(w2T + 512L * 2048);   // [1536]
  bf16_t* xb  = (bf16_t*)(wsp +   8 * Mi);       // 32 MiB
  bf16_t* qkb = (bf16_t*)(wsp +  40 * Mi);       // 64 MiB [32768][1024]
  bf16_t* vT  = (bf16_t*)(wsp + 104 * Mi);       // 32 MiB
  bf16_t* E   = (bf16_t*)(wsp + 136 * Mi);       // 64 MiB
  bf16_t* ob  = xb;                              // PV out
  bf16_t* x1b = qkb;                             // 32 MiB at off 40
  bf16_t* h   = (bf16_t*)(wsp + 72 * Mi);        // 128 MiB [32768][2048]

  // 1. cast x -> bf16
  cast_to_bf16<<<dim3((unsigned)(S / 4 / 256)), 256, 0, stream>>>(x, xb, S);

  // 2. weight transposes + bias concat
  transpose_cast<<<dim3(16, 16), 256, 0, stream>>>(wq, wqkvT,               512, 512);
  transpose_cast<<<dim3(16, 16), 256, 0, stream>>>(wk, wqkvT + 512L * 512,  512, 512);
  transpose_cast<<<dim3(16, 16), 256, 0, stream>>>(wv, wqkvT + 1024L * 512, 512, 512);
  transpose_cast<<<dim3(16, 16), 256, 0, stream>>>(wp, wpT, 512, 512);
  transpose_cast<<<dim3(64, 16), 256, 0, stream>>>(w1, w1T, 512, 2048);
  transpose_cast<<<dim3(16, 64), 256, 0, stream>>>(w2, w2T, 2048, 512);
  concat_bias<<<dim3(6), 256, 0, stream>>>(bq, bk, bv, bqkv);

  // 3. merged QKV GEMM (M=32768, N=1536, K=512), split epilogue:
  //    cols<1024 -> qkb (ldc=1024); cols>=1024 -> vT transposed per batch
  gemm_bt<5, true><<<dim3(12, 256, 1), 256, 0, stream>>>(
      xb, wqkvT, bqkv, qkb, vT, 32768, 1536, 512, 512, 512, 1024, 0, 0, 0, 0.f);

  // 4. attention in 2 chunks of 8 batches
  for (int cgrp = 0; cgrp < 2; cgrp++) {
    const long qoff = (long)cgrp * 8 * 2048 * 1024;
    // E = (q k^T) * 1/sqrt(512)  (M=N=2048, K=512, z=8)
    gemm_bt<2, false><<<dim3(16, 16, 8), 256, 0, stream>>>(
        qkb + qoff, qkb + qoff + 512, nullptr, E, nullptr,
        2048, 2048, 512, 1024, 1024, 2048,
        2048L * 1024, 2048L * 1024, 2048L * 2048, 0.04419417382f);
    // softmax rows
    softmax2048<<<dim3(16384), 256, 0, stream>>>(E);
    // out = P V  (M=2048, N=512, K=2048, z=8)
    gemm_bt<1, false><<<dim3(4, 16, 8), 256, 0, stream>>>(
        E, vT + (long)cgrp * 8 * 512 * 2048, nullptr,
        ob + (long)cgrp * 8 * 2048 * 512, nullptr,
        2048, 512, 2048, 2048, 2048, 512,
        2048L * 2048, 512L * 2048, 2048L * 512, 0.f);
  }

  // 5. proj -> d_out (fp32 scratch)
  gemm_bt<0, true><<<dim3(4, 256, 1), 256, 0, stream>>>(
      ob, wpT, bp, (float*)d_out, nullptr,
      32768, 512, 512, 512, 512, 512, 0, 0, 0, 0.f);

  // 6. x1b = bf16( LN(x + proj) )
  add_ln<false, false, true><<<dim3(32768), 128, 0, stream>>>(
      x, (float*)d_out, g1, be1, nullptr, x1b);

  // 7. FF1: h = gelu(x1 w1 + b1)  (M=32768, N=2048, K=512)
  gemm_bt<3, true><<<dim3(16, 256, 1), 256, 0, stream>>>(
      x1b, w1T, b1, h, nullptr, 32768, 2048, 512, 512, 512, 2048, 0, 0, 0, 0.f);

  // 8. FF2: ff = h w2 + b2 -> d_out (fp32)  (M=32768, N=512, K=2048)
  gemm_bt<0, true><<<dim3(4, 256, 1), 256, 0, stream>>>(
      h, w2T, b2, (float*)d_out, nullptr,
      32768, 512, 2048, 2048, 2048, 512, 0, 0, 0, 0.f);

  // 9. out = LN(x1 + ff), in place on d_out
  add_ln<true, true, false><<<dim3(32768), 128, 0, stream>>>(
      x1b, (float*)d_out, g2, be2, (float*)d_out, nullptr);
}

// Round 5
// 677.165 us; speedup vs baseline: 1.7840x; 1.0396x over previous
//
#include <hip/hip_runtime.h>
#include <cmath>

typedef __bf16 bf16_t;
typedef __bf16 bf16x8 __attribute__((ext_vector_type(8)));
typedef __bf16 bf16x4 __attribute__((ext_vector_type(4)));
typedef float f32x4 __attribute__((ext_vector_type(4)));

#define DEV_INLINE __device__ __forceinline__

DEV_INLINE void gload_lds16(const void* g, void* l) {
  __builtin_amdgcn_global_load_lds(
      (const __attribute__((address_space(1))) void*)g,
      (__attribute__((address_space(3))) void*)l, 16, 0, 0);
}

// ---------------------------------------------------------------------------
// GEMM: C = A[M][.lda] * B^T (B stored [N][.ldb]) + bias, fused epilogue.
// EPI: 0 = fp32 out, 1 = bf16 out, 2 = bf16 out *scale (no bias), 3 = bf16
//      gelu(out), 5 = merged-QKV split: cols<1024 -> bf16 C[row][c] (ldc),
//      cols>=1024 -> V written TRANSPOSED per batch into vTaux[b][c-1024][n].
// 128x128 tile, BK=32, 256 threads = 4 waves (2x2), wave tile 64x64.
// Pipeline: 4 LDS buffers, lookahead 3, raw s_barrier + counted vmcnt
// (never drains to 0 in steady state — T3/T4). LDS XOR-swizzle (T2):
// byte ^= ((row>>1)&3)<<4 on BOTH stage-source and ds_read (involution).
// ---------------------------------------------------------------------------
template<int EPI, bool HAS_BIAS>
__global__ __launch_bounds__(256, 2)
void gemm_bt(const bf16_t* __restrict__ A, const bf16_t* __restrict__ B,
             const float* __restrict__ bias, void* __restrict__ C,
             bf16_t* __restrict__ vTaux,
             int M, int N, int K, int lda, int ldb, int ldc,
             long sA, long sB, long sC, float scale)
{
  // lds[buf][0]=A tile [128][32] bf16, lds[buf][1]=B tile. 64 KiB total.
  __shared__ alignas(16) bf16_t lds[4][2][4096];
  const int b = blockIdx.z;
  A += (long)b * sA;
  B += (long)b * sB;
  const int t  = threadIdx.x;
  const int l  = t & 63;
  const int w  = t >> 6;
  const int wr = (w >> 1) * 64;
  const int wc = (w & 1) * 64;
  const int m0 = blockIdx.y * 128;
  const int n0 = blockIdx.x * 128;

  // --- staging geometry: thread t covers LDS bytes [t*16) and [4096+t*16)
  // of each tensor region: rows r0=t/4 and r1=r0+64, within-row byte (t&3)*16.
  // Global source col-byte is XOR-swizzled so that linear LDS dest +
  // swizzled ds_read = identity (rule #21 both-sides).
  const int r0 = t >> 2;
  const int r1 = r0 + 64;
  const int wb = (t & 3) * 16;
  const int cb0 = wb ^ (((r0 >> 1) & 3) << 4);
  const int cb1 = wb ^ (((r1 >> 1) & 3) << 4);
  const bf16_t* gA0 = A + (long)(m0 + r0) * lda + (cb0 >> 1);
  const bf16_t* gA1 = A + (long)(m0 + r1) * lda + (cb1 >> 1);
  const bf16_t* gB0 = B + (long)(n0 + r0) * ldb + (cb0 >> 1);
  const bf16_t* gB1 = B + (long)(n0 + r1) * ldb + (cb1 >> 1);

#define STAGE(kt, q) do {                                   \
    const long kofs_ = (long)(kt) * 32;                     \
    gload_lds16(gA0 + kofs_, &lds[q][0][t * 8]);            \
    gload_lds16(gA1 + kofs_, &lds[q][0][2048 + t * 8]);     \
    gload_lds16(gB0 + kofs_, &lds[q][1][t * 8]);            \
    gload_lds16(gB1 + kofs_, &lds[q][1][2048 + t * 8]);     \
  } while (0)

  // --- fragment read offsets (elements), XOR-swizzled per row
  const int fr  = l & 15;
  const int kkb = (l >> 4) * 16;   // k-byte within 64B row
  int offA[4], offB[4];
#pragma unroll
  for (int mi = 0; mi < 4; mi++) {
    const int row = wr + mi * 16 + fr;
    offA[mi] = row * 32 + ((kkb ^ (((row >> 1) & 3) << 4)) >> 1);
  }
#pragma unroll
  for (int ni = 0; ni < 4; ni++) {
    const int row = wc + ni * 16 + fr;
    offB[ni] = row * 32 + ((kkb ^ (((row >> 1) & 3) << 4)) >> 1);
  }

  f32x4 acc[4][4] = {};

  const int NT = K >> 5;
  STAGE(0, 0);
  STAGE(1, 1);
  STAGE(2, 2);

  for (int kt = 0; kt < NT; ++kt) {
    const int q = kt & 3;
    if (kt + 3 < NT) {
      STAGE(kt + 3, (kt + 3) & 3);
      asm volatile("s_waitcnt vmcnt(12)" ::: "memory");   // tile kt complete
    } else if (kt + 3 == NT) {
      asm volatile("s_waitcnt vmcnt(8)" ::: "memory");
    } else if (kt + 2 == NT) {
      asm volatile("s_waitcnt vmcnt(4)" ::: "memory");
    } else {
      asm volatile("s_waitcnt vmcnt(0)" ::: "memory");
    }
    __builtin_amdgcn_sched_barrier(0);
    __builtin_amdgcn_s_barrier();      // tile kt visible to all waves

    bf16x8 af[4], bfr[4];
#pragma unroll
    for (int mi = 0; mi < 4; mi++)
      af[mi] = *(const bf16x8*)&lds[q][0][offA[mi]];
#pragma unroll
    for (int ni = 0; ni < 4; ni++)
      bfr[ni] = *(const bf16x8*)&lds[q][1][offB[ni]];
#pragma unroll
    for (int mi = 0; mi < 4; mi++)
#pragma unroll
      for (int ni = 0; ni < 4; ni++)
        acc[mi][ni] = __builtin_amdgcn_mfma_f32_16x16x32_bf16(
            af[mi], bfr[ni], acc[mi][ni], 0, 0, 0);

    __builtin_amdgcn_sched_barrier(0);
    __builtin_amdgcn_s_barrier();      // all waves done reading buf q
  }
#undef STAGE

  // C/D layout: col = lane&15, row = 4*(lane>>4) + reg
  const long cb = (long)b * sC;
  const int rbase = m0 + wr + (l >> 4) * 4;
#pragma unroll
  for (int mi = 0; mi < 4; mi++) {
    const int row0 = rbase + mi * 16;
#pragma unroll
    for (int ni = 0; ni < 4; ni++) {
      const int c = n0 + wc + ni * 16 + fr;
      float bias_v = 0.f;
      if constexpr (HAS_BIAS) bias_v = bias[c];
      float vals[4];
#pragma unroll
      for (int r = 0; r < 4; r++) {
        float v = acc[mi][ni][r] + bias_v;
        if constexpr (EPI == 2) v *= scale;
        if constexpr (EPI == 3) v = 0.5f * v * (1.f + erff(v * 0.70710678118f));
        vals[r] = v;
      }
      if constexpr (EPI == 5) {
        if (c < 1024) {           // block-uniform branch (n0 128-aligned)
#pragma unroll
          for (int r = 0; r < 4; r++)
            ((bf16_t*)C)[(long)(row0 + r) * ldc + c] = (bf16_t)vals[r];
        } else {
          const int bb = row0 >> 11;        // batch
          const int n  = row0 & 2047;       // token within batch (mult of 4)
          bf16x4 pk = { (bf16_t)vals[0], (bf16_t)vals[1],
                        (bf16_t)vals[2], (bf16_t)vals[3] };
          *(bf16x4*)&vTaux[(long)bb * (512 * 2048) + (long)(c - 1024) * 2048 + n] = pk;
        }
      } else {
#pragma unroll
        for (int r = 0; r < 4; r++) {
          const long idx = cb + (long)(row0 + r) * ldc + c;
          if constexpr (EPI == 0) ((float*)C)[idx] = vals[r];
          else                    ((bf16_t*)C)[idx] = (bf16_t)vals[r];
        }
      }
    }
  }
}

// ---------------------------------------------------------------------------
// Transpose + cast to bf16: in [R][Cc] (fp32) -> out [Cc][R] (bf16).
// ---------------------------------------------------------------------------
__global__ __launch_bounds__(256)
void transpose_cast(const float* __restrict__ in, bf16_t* __restrict__ out,
                    int R, int Cc)
{
  __shared__ float tile[32][33];
  const int c0 = blockIdx.x * 32;
  const int r0 = blockIdx.y * 32;
  const int tx = threadIdx.x & 31;
  const int ty = threadIdx.x >> 5;
#pragma unroll
  for (int i = 0; i < 32; i += 8)
    tile[ty + i][tx] = in[(long)(r0 + ty + i) * Cc + (c0 + tx)];
  __syncthreads();
#pragma unroll
  for (int i = 0; i < 32; i += 8)
    out[(long)(c0 + ty + i) * R + (r0 + tx)] = (bf16_t)tile[tx][ty + i];
}

__global__ __launch_bounds__(256)
void cast_to_bf16(const float* __restrict__ in, bf16_t* __restrict__ out, long n)
{
  const long i = ((long)blockIdx.x * 256 + threadIdx.x) * 4;
  if (i >= n) return;
  const float4 v = *(const float4*)&in[i];
  bf16x4 o = { (bf16_t)v.x, (bf16_t)v.y, (bf16_t)v.z, (bf16_t)v.w };
  *(bf16x4*)&out[i] = o;
}

// concat bq|bk|bv -> bqkv[1536]
__global__ __launch_bounds__(256)
void concat_bias(const float* __restrict__ a, const float* __restrict__ b,
                 const float* __restrict__ c, float* __restrict__ o)
{
  const int i = blockIdx.x * 256 + threadIdx.x;
  if (i < 512) o[i] = a[i];
  else if (i < 1024) o[i] = b[i - 512];
  else if (i < 1536) o[i] = c[i - 1024];
}

// ---------------------------------------------------------------------------
// Row softmax over 2048 bf16 elements, in place. One 256-thread block per row.
// ---------------------------------------------------------------------------
__global__ __launch_bounds__(256)
void softmax2048(bf16_t* __restrict__ E)
{
  const long row = blockIdx.x;
  bf16_t* p = E + row * 2048;
  const int t = threadIdx.x;
  bf16x8 xv = *(const bf16x8*)&p[t * 8];
  float v[8];
#pragma unroll
  for (int j = 0; j < 8; j++) v[j] = (float)xv[j];
  float m = v[0];
#pragma unroll
  for (int j = 1; j < 8; j++) m = fmaxf(m, v[j]);
  for (int o = 32; o; o >>= 1) m = fmaxf(m, __shfl_xor(m, o));
  __shared__ float redm[4];
  __shared__ float reds[4];
  if ((t & 63) == 0) redm[t >> 6] = m;
  __syncthreads();
  m = fmaxf(fmaxf(redm[0], redm[1]), fmaxf(redm[2], redm[3]));
  float s = 0.f;
#pragma unroll
  for (int j = 0; j < 8; j++) { v[j] = __expf(v[j] - m); s += v[j]; }
  for (int o = 32; o; o >>= 1) s += __shfl_xor(s, o);
  if ((t & 63) == 0) reds[t >> 6] = s;
  __syncthreads();
  s = reds[0] + reds[1] + reds[2] + reds[3];
  const float inv = 1.f / s;
  bf16x8 ov;
#pragma unroll
  for (int j = 0; j < 8; j++) ov[j] = (bf16_t)(v[j] * inv);
  *(bf16x8*)&p[t * 8] = ov;
}

// ---------------------------------------------------------------------------
// Fused residual add + LayerNorm over rows of 512.
// ---------------------------------------------------------------------------
template<bool A_BF16, bool EMIT_F32, bool EMIT_BF16>
__global__ __launch_bounds__(128)
void add_ln(const void* __restrict__ xa_, const float* __restrict__ xadd,
            const float* __restrict__ g, const float* __restrict__ be,
            float* __restrict__ y, bf16_t* __restrict__ yb)
{
  const long row = blockIdx.x;
  const int c = threadIdx.x * 4;
  float av[4];
  if constexpr (A_BF16) {
    const bf16_t* xa = (const bf16_t*)xa_;
    bf16x4 a = *(const bf16x4*)&xa[row * 512 + c];
#pragma unroll
    for (int j = 0; j < 4; j++) av[j] = (float)a[j];
  } else {
    const float* xa = (const float*)xa_;
    const float4 a = *(const float4*)&xa[row * 512 + c];
    av[0] = a.x; av[1] = a.y; av[2] = a.z; av[3] = a.w;
  }
  const float4 bb = *(const float4*)&xadd[row * 512 + c];
  float vv[4] = { av[0] + bb.x, av[1] + bb.y, av[2] + bb.z, av[3] + bb.w };
  float s = 0.f, s2 = 0.f;
#pragma unroll
  for (int j = 0; j < 4; j++) { s += vv[j]; s2 += vv[j] * vv[j]; }
  for (int o = 32; o; o >>= 1) { s += __shfl_xor(s, o); s2 += __shfl_xor(s2, o); }
  __shared__ float r0[2], r1[2];
  const int w = threadIdx.x >> 6;
  if ((threadIdx.x & 63) == 0) { r0[w] = s; r1[w] = s2; }
  __syncthreads();
  s = r0[0] + r0[1]; s2 = r1[0] + r1[1];
  const float mu = s * (1.f / 512.f);
  const float var = s2 * (1.f / 512.f) - mu * mu;
  const float rstd = rsqrtf(var + 1e-5f);
  const float4 gg = *(const float4*)&g[c];
  const float4 bev = *(const float4*)&be[c];
  float o0 = (vv[0] - mu) * rstd * gg.x + bev.x;
  float o1 = (vv[1] - mu) * rstd * gg.y + bev.y;
  float o2 = (vv[2] - mu) * rstd * gg.z + bev.z;
  float o3 = (vv[3] - mu) * rstd * gg.w + bev.w;
  if constexpr (EMIT_F32) {
    float4 yo = { o0, o1, o2, o3 };
    *(float4*)&y[row * 512 + c] = yo;
  }
  if constexpr (EMIT_BF16) {
    bf16x4 ob = { (bf16_t)o0, (bf16_t)o1, (bf16_t)o2, (bf16_t)o3 };
    *(bf16x4*)&yb[row * 512 + c] = ob;
  }
}

// ---------------------------------------------------------------------------
extern "C" void kernel_launch(void* const* d_in, const int* in_sizes, int n_in,
                              void* d_out, int out_size, void* d_ws, size_t ws_size,
                              hipStream_t stream)
{
  const float* x   = (const float*)d_in[0];
  const float* wq  = (const float*)d_in[1];
  const float* bq  = (const float*)d_in[2];
  const float* wk  = (const float*)d_in[3];
  const float* bk  = (const float*)d_in[4];
  const float* wv  = (const float*)d_in[5];
  const float* bv  = (const float*)d_in[6];
  const float* wp  = (const float*)d_in[7];
  const float* bp  = (const float*)d_in[8];
  const float* w1  = (const float*)d_in[9];
  const float* b1  = (const float*)d_in[10];
  const float* w2  = (const float*)d_in[11];
  const float* b2  = (const float*)d_in[12];
  const float* g1  = (const float*)d_in[13];
  const float* be1 = (const float*)d_in[14];
  const float* g2  = (const float*)d_in[15];
  const float* be2 = (const float*)d_in[16];

  const long S = 16L * 2048 * 512;   // tokens*D
  const long Mi = 1L << 20;

  // Workspace (200 MiB):
  //   0: weights (wqkvT 1.5, wpT 0.5, w1T 2, w2T 2, bqkv) -> 8 MiB region
  //   8: xb 32            (reused as ob after QKV)
  //  40: qkb 64 [32768][1024]  (reused: x1b at 40..72, h spans 72..200)
  // 104: vT 32 [16][512][2048]
  // 136: E  64 (8-batch score chunk; 2 passes)
  const size_t NEED = (size_t)200 * Mi;
  if (ws_size < NEED) return;

  char* wsp = (char*)d_ws;
  bf16_t* wqkvT = (bf16_t*)(wsp + 0);            // [1536][512]
  bf16_t* wpT   = wqkvT + 1536L * 512;           // [512][512]
  bf16_t* w1T   = wpT + 512L * 512;              // [2048][512]
  bf16_t* w2T   = w1T + 2048L * 512;             // [512][2048]
  float*  bqkv  = (float*)(w2T + 512L * 2048);   // [1536]
  bf16_t* xb  = (bf16_t*)(wsp +   8 * Mi);       // 32 MiB
  bf16_t* qkb = (bf16_t*)(wsp +  40 * Mi);       // 64 MiB [32768][1024]
  bf16_t* vT  = (bf16_t*)(wsp + 104 * Mi);       // 32 MiB
  bf16_t* E   = (bf16_t*)(wsp + 136 * Mi);       // 64 MiB
  bf16_t* ob  = xb;                              // PV out
  bf16_t* x1b = qkb;                             // 32 MiB at off 40
  bf16_t* h   = (bf16_t*)(wsp + 72 * Mi);        // 128 MiB [32768][2048]

  // 1. cast x -> bf16
  cast_to_bf16<<<dim3((unsigned)(S / 4 / 256)), 256, 0, stream>>>(x, xb, S);

  // 2. weight transposes + bias concat
  transpose_cast<<<dim3(16, 16), 256, 0, stream>>>(wq, wqkvT,               512, 512);
  transpose_cast<<<dim3(16, 16), 256, 0, stream>>>(wk, wqkvT + 512L * 512,  512, 512);
  transpose_cast<<<dim3(16, 16), 256, 0, stream>>>(wv, wqkvT + 1024L * 512, 512, 512);
  transpose_cast<<<dim3(16, 16), 256, 0, stream>>>(wp, wpT, 512, 512);
  transpose_cast<<<dim3(64, 16), 256, 0, stream>>>(w1, w1T, 512, 2048);
  transpose_cast<<<dim3(16, 64), 256, 0, stream>>>(w2, w2T, 2048, 512);
  concat_bias<<<dim3(6), 256, 0, stream>>>(bq, bk, bv, bqkv);

  // 3. merged QKV GEMM (M=32768, N=1536, K=512), split epilogue:
  //    cols<1024 -> qkb (ldc=1024); cols>=1024 -> vT transposed per batch
  gemm_bt<5, true><<<dim3(12, 256, 1), 256, 0, stream>>>(
      xb, wqkvT, bqkv, qkb, vT, 32768, 1536, 512, 512, 512, 1024, 0, 0, 0, 0.f);

  // 4. attention in 2 chunks of 8 batches
  for (int cgrp = 0; cgrp < 2; cgrp++) {
    const long qoff = (long)cgrp * 8 * 2048 * 1024;
    // E = (q k^T) * 1/sqrt(512)  (M=N=2048, K=512, z=8)
    gemm_bt<2, false><<<dim3(16, 16, 8), 256, 0, stream>>>(
        qkb + qoff, qkb + qoff + 512, nullptr, E, nullptr,
        2048, 2048, 512, 1024, 1024, 2048,
        2048L * 1024, 2048L * 1024, 2048L * 2048, 0.04419417382f);
    // softmax rows
    softmax2048<<<dim3(16384), 256, 0, stream>>>(E);
    // out = P V  (M=2048, N=512, K=2048, z=8)
    gemm_bt<1, false><<<dim3(4, 16, 8), 256, 0, stream>>>(
        E, vT + (long)cgrp * 8 * 512 * 2048, nullptr,
        ob + (long)cgrp * 8 * 2048 * 512, nullptr,
        2048, 512, 2048, 2048, 2048, 512,
        2048L * 2048, 512L * 2048, 2048L * 512, 0.f);
  }

  // 5. proj -> d_out (fp32 scratch)
  gemm_bt<0, true><<<dim3(4, 256, 1), 256, 0, stream>>>(
      ob, wpT, bp, (float*)d_out, nullptr,
      32768, 512, 512, 512, 512, 512, 0, 0, 0, 0.f);

  // 6. x1b = bf16( LN(x + proj) )
  add_ln<false, false, true><<<dim3(32768), 128, 0, stream>>>(
      x, (float*)d_out, g1, be1, nullptr, x1b);

  // 7. FF1: h = gelu(x1 w1 + b1)  (M=32768, N=2048, K=512)
  gemm_bt<3, true><<<dim3(16, 256, 1), 256, 0, stream>>>(
      x1b, w1T, b1, h, nullptr, 32768, 2048, 512, 512, 512, 2048, 0, 0, 0, 0.f);

  // 8. FF2: ff = h w2 + b2 -> d_out (fp32)  (M=32768, N=512, K=2048)
  gemm_bt<0, true><<<dim3(4, 256, 1), 256, 0, stream>>>(
      h, w2T, b2, (float*)d_out, nullptr,
      32768, 512, 2048, 2048, 2048, 512, 0, 0, 0, 0.f);

  // 9. out = LN(x1 + ff), in place on d_out
  add_ln<true, true, false><<<dim3(32768), 128, 0, stream>>>(
      x1b, (float*)d_out, g2, be2, (float*)d_out, nullptr);
}

// Round 6
// 636.867 us; speedup vs baseline: 1.8969x; 1.0633x over previous
//
#include <hip/hip_runtime.h>
#include <cmath>

typedef __bf16 bf16_t;
typedef __bf16 bf16x8 __attribute__((ext_vector_type(8)));
typedef __bf16 bf16x4 __attribute__((ext_vector_type(4)));
typedef float f32x4 __attribute__((ext_vector_type(4)));

#define DEV_INLINE __device__ __forceinline__

DEV_INLINE void gload_lds16(const void* g, void* l) {
  __builtin_amdgcn_global_load_lds(
      (const __attribute__((address_space(1))) void*)g,
      (__attribute__((address_space(3))) void*)l, 16, 0, 0);
}

// ---------------------------------------------------------------------------
// GEMM: C = A[M][.lda] * B^T (B stored [N][.ldb]) + bias, fused epilogue.
// EPI: 0 = fp32 out, 1 = bf16 out, 2 = bf16 out *scale (no bias), 3 = bf16
//      gelu(out), 5 = merged-QKV split: cols<1024 -> bf16 C[row][c] (ldc),
//      cols>=1024 -> V written TRANSPOSED per batch into vTaux[b][c-1024][n].
// 128x128 tile, BK=32, 256 threads = 4 waves (2x2), wave tile 64x64.
// Pipeline: 3-buffer LDS ring (48 KiB -> 3 blocks/CU), lookahead 2,
// ONE raw s_barrier per k-iter (STAGE placed post-barrier: the target buffer's
// readers all passed this barrier, so the end-of-iter barrier is unnecessary),
// counted vmcnt(4) steady state (never drains until the final iter) — T3/T4.
// LDS XOR-swizzle (T2): byte ^= ((row>>1)&3)<<4 on BOTH stage-source and
// ds_read (involution) — keeps ds_read_b128 conflict-free (verified: 0).
// ---------------------------------------------------------------------------
template<int EPI, bool HAS_BIAS>
__global__ __launch_bounds__(256, 2)
void gemm_bt(const bf16_t* __restrict__ A, const bf16_t* __restrict__ B,
             const float* __restrict__ bias, void* __restrict__ C,
             bf16_t* __restrict__ vTaux,
             int M, int N, int K, int lda, int ldb, int ldc,
             long sA, long sB, long sC, float scale)
{
  // lds[buf][0]=A tile [128][32] bf16, lds[buf][1]=B tile. 48 KiB total.
  __shared__ alignas(16) bf16_t lds[3][2][4096];
  const int b = blockIdx.z;
  A += (long)b * sA;
  B += (long)b * sB;
  const int t  = threadIdx.x;
  const int l  = t & 63;
  const int w  = t >> 6;
  const int wr = (w >> 1) * 64;
  const int wc = (w & 1) * 64;
  const int m0 = blockIdx.y * 128;
  const int n0 = blockIdx.x * 128;

  // staging geometry: thread t covers rows r0=t/4, r1=r0+64; byte (t&3)*16.
  // Source col-byte XOR-swizzled; LDS dest linear (rule #21 both-sides).
  const int r0 = t >> 2;
  const int r1 = r0 + 64;
  const int wb = (t & 3) * 16;
  const int cb0 = wb ^ (((r0 >> 1) & 3) << 4);
  const int cb1 = wb ^ (((r1 >> 1) & 3) << 4);
  const bf16_t* gA0 = A + (long)(m0 + r0) * lda + (cb0 >> 1);
  const bf16_t* gA1 = A + (long)(m0 + r1) * lda + (cb1 >> 1);
  const bf16_t* gB0 = B + (long)(n0 + r0) * ldb + (cb0 >> 1);
  const bf16_t* gB1 = B + (long)(n0 + r1) * ldb + (cb1 >> 1);

#define STAGE(kt, q) do {                                   \
    const long kofs_ = (long)(kt) * 32;                     \
    gload_lds16(gA0 + kofs_, &lds[q][0][t * 8]);            \
    gload_lds16(gA1 + kofs_, &lds[q][0][2048 + t * 8]);     \
    gload_lds16(gB0 + kofs_, &lds[q][1][t * 8]);            \
    gload_lds16(gB1 + kofs_, &lds[q][1][2048 + t * 8]);     \
  } while (0)

  // fragment read offsets (elements), XOR-swizzled per row
  const int fr  = l & 15;
  const int kkb = (l >> 4) * 16;   // k-byte within 64B row
  int offA[4], offB[4];
#pragma unroll
  for (int mi = 0; mi < 4; mi++) {
    const int row = wr + mi * 16 + fr;
    offA[mi] = row * 32 + ((kkb ^ (((row >> 1) & 3) << 4)) >> 1);
  }
#pragma unroll
  for (int ni = 0; ni < 4; ni++) {
    const int row = wc + ni * 16 + fr;
    offB[ni] = row * 32 + ((kkb ^ (((row >> 1) & 3) << 4)) >> 1);
  }

  f32x4 acc[4][4] = {};

  const int NT = K >> 5;
  STAGE(0, 0);
  STAGE(1, 1);

  int q = 0;                 // buffer holding tile kt
  for (int kt = 0; kt < NT; ++kt) {
    // tile kt landed when at most tiles kt+1,(kt+2 not yet issued) remain:
    if (kt < NT - 1) asm volatile("s_waitcnt vmcnt(4)" ::: "memory");
    else             asm volatile("s_waitcnt vmcnt(0)" ::: "memory");
    __builtin_amdgcn_sched_barrier(0);
    __builtin_amdgcn_s_barrier();   // publishes tile kt; retires kt-1's reads

    if (kt + 2 < NT) {
      int qs = q + 2; if (qs >= 3) qs -= 3;     // == (kt+2)%3, last read kt-1
      STAGE(kt + 2, qs);
    }

    bf16x8 af[4], bfr[4];
#pragma unroll
    for (int mi = 0; mi < 4; mi++)
      af[mi] = *(const bf16x8*)&lds[q][0][offA[mi]];
#pragma unroll
    for (int ni = 0; ni < 4; ni++)
      bfr[ni] = *(const bf16x8*)&lds[q][1][offB[ni]];
#pragma unroll
    for (int mi = 0; mi < 4; mi++)
#pragma unroll
      for (int ni = 0; ni < 4; ni++)
        acc[mi][ni] = __builtin_amdgcn_mfma_f32_16x16x32_bf16(
            af[mi], bfr[ni], acc[mi][ni], 0, 0, 0);

    if (++q == 3) q = 0;
  }
#undef STAGE

  // C/D layout: col = lane&15, row = 4*(lane>>4) + reg
  const long cb = (long)b * sC;
  const int rbase = m0 + wr + (l >> 4) * 4;
#pragma unroll
  for (int mi = 0; mi < 4; mi++) {
    const int row0 = rbase + mi * 16;
#pragma unroll
    for (int ni = 0; ni < 4; ni++) {
      const int c = n0 + wc + ni * 16 + fr;
      float bias_v = 0.f;
      if constexpr (HAS_BIAS) bias_v = bias[c];
      float vals[4];
#pragma unroll
      for (int r = 0; r < 4; r++) {
        float v = acc[mi][ni][r] + bias_v;
        if constexpr (EPI == 2) v *= scale;
        if constexpr (EPI == 3) v = 0.5f * v * (1.f + erff(v * 0.70710678118f));
        vals[r] = v;
      }
      if constexpr (EPI == 5) {
        if (c < 1024) {           // block-uniform branch (n0 128-aligned)
#pragma unroll
          for (int r = 0; r < 4; r++)
            ((bf16_t*)C)[(long)(row0 + r) * ldc + c] = (bf16_t)vals[r];
        } else {
          const int bb = row0 >> 11;        // batch
          const int n  = row0 & 2047;       // token within batch (mult of 4)
          bf16x4 pk = { (bf16_t)vals[0], (bf16_t)vals[1],
                        (bf16_t)vals[2], (bf16_t)vals[3] };
          *(bf16x4*)&vTaux[(long)bb * (512 * 2048) + (long)(c - 1024) * 2048 + n] = pk;
        }
      } else {
#pragma unroll
        for (int r = 0; r < 4; r++) {
          const long idx = cb + (long)(row0 + r) * ldc + c;
          if constexpr (EPI == 0) ((float*)C)[idx] = vals[r];
          else                    ((bf16_t*)C)[idx] = (bf16_t)vals[r];
        }
      }
    }
  }
}

// ---------------------------------------------------------------------------
// Transpose + cast to bf16: in [R][Cc] (fp32) -> out [Cc][R] (bf16).
// ---------------------------------------------------------------------------
__global__ __launch_bounds__(256)
void transpose_cast(const float* __restrict__ in, bf16_t* __restrict__ out,
                    int R, int Cc)
{
  __shared__ float tile[32][33];
  const int c0 = blockIdx.x * 32;
  const int r0 = blockIdx.y * 32;
  const int tx = threadIdx.x & 31;
  const int ty = threadIdx.x >> 5;
#pragma unroll
  for (int i = 0; i < 32; i += 8)
    tile[ty + i][tx] = in[(long)(r0 + ty + i) * Cc + (c0 + tx)];
  __syncthreads();
#pragma unroll
  for (int i = 0; i < 32; i += 8)
    out[(long)(c0 + ty + i) * R + (r0 + tx)] = (bf16_t)tile[tx][ty + i];
}

__global__ __launch_bounds__(256)
void cast_to_bf16(const float* __restrict__ in, bf16_t* __restrict__ out, long n)
{
  const long i = ((long)blockIdx.x * 256 + threadIdx.x) * 4;
  if (i >= n) return;
  const float4 v = *(const float4*)&in[i];
  bf16x4 o = { (bf16_t)v.x, (bf16_t)v.y, (bf16_t)v.z, (bf16_t)v.w };
  *(bf16x4*)&out[i] = o;
}

// concat bq|bk|bv -> bqkv[1536]
__global__ __launch_bounds__(256)
void concat_bias(const float* __restrict__ a, const float* __restrict__ b,
                 const float* __restrict__ c, float* __restrict__ o)
{
  const int i = blockIdx.x * 256 + threadIdx.x;
  if (i < 512) o[i] = a[i];
  else if (i < 1024) o[i] = b[i - 512];
  else if (i < 1536) o[i] = c[i - 1024];
}

// ---------------------------------------------------------------------------
// Row softmax over 2048 bf16 elements, in place. One 256-thread block per row.
// ---------------------------------------------------------------------------
__global__ __launch_bounds__(256)
void softmax2048(bf16_t* __restrict__ E)
{
  const long row = blockIdx.x;
  bf16_t* p = E + row * 2048;
  const int t = threadIdx.x;
  bf16x8 xv = *(const bf16x8*)&p[t * 8];
  float v[8];
#pragma unroll
  for (int j = 0; j < 8; j++) v[j] = (float)xv[j];
  float m = v[0];
#pragma unroll
  for (int j = 1; j < 8; j++) m = fmaxf(m, v[j]);
  for (int o = 32; o; o >>= 1) m = fmaxf(m, __shfl_xor(m, o));
  __shared__ float redm[4];
  __shared__ float reds[4];
  if ((t & 63) == 0) redm[t >> 6] = m;
  __syncthreads();
  m = fmaxf(fmaxf(redm[0], redm[1]), fmaxf(redm[2], redm[3]));
  float s = 0.f;
#pragma unroll
  for (int j = 0; j < 8; j++) { v[j] = __expf(v[j] - m); s += v[j]; }
  for (int o = 32; o; o >>= 1) s += __shfl_xor(s, o);
  if ((t & 63) == 0) reds[t >> 6] = s;
  __syncthreads();
  s = reds[0] + reds[1] + reds[2] + reds[3];
  const float inv = 1.f / s;
  bf16x8 ov;
#pragma unroll
  for (int j = 0; j < 8; j++) ov[j] = (bf16_t)(v[j] * inv);
  *(bf16x8*)&p[t * 8] = ov;
}

// ---------------------------------------------------------------------------
// Fused residual add + LayerNorm over rows of 512.
// ---------------------------------------------------------------------------
template<bool A_BF16, bool EMIT_F32, bool EMIT_BF16>
__global__ __launch_bounds__(128)
void add_ln(const void* __restrict__ xa_, const float* __restrict__ xadd,
            const float* __restrict__ g, const float* __restrict__ be,
            float* __restrict__ y, bf16_t* __restrict__ yb)
{
  const long row = blockIdx.x;
  const int c = threadIdx.x * 4;
  float av[4];
  if constexpr (A_BF16) {
    const bf16_t* xa = (const bf16_t*)xa_;
    bf16x4 a = *(const bf16x4*)&xa[row * 512 + c];
#pragma unroll
    for (int j = 0; j < 4; j++) av[j] = (float)a[j];
  } else {
    const float* xa = (const float*)xa_;
    const float4 a = *(const float4*)&xa[row * 512 + c];
    av[0] = a.x; av[1] = a.y; av[2] = a.z; av[3] = a.w;
  }
  const float4 bb = *(const float4*)&xadd[row * 512 + c];
  float vv[4] = { av[0] + bb.x, av[1] + bb.y, av[2] + bb.z, av[3] + bb.w };
  float s = 0.f, s2 = 0.f;
#pragma unroll
  for (int j = 0; j < 4; j++) { s += vv[j]; s2 += vv[j] * vv[j]; }
  for (int o = 32; o; o >>= 1) { s += __shfl_xor(s, o); s2 += __shfl_xor(s2, o); }
  __shared__ float r0[2], r1[2];
  const int w = threadIdx.x >> 6;
  if ((threadIdx.x & 63) == 0) { r0[w] = s; r1[w] = s2; }
  __syncthreads();
  s = r0[0] + r0[1]; s2 = r1[0] + r1[1];
  const float mu = s * (1.f / 512.f);
  const float var = s2 * (1.f / 512.f) - mu * mu;
  const float rstd = rsqrtf(var + 1e-5f);
  const float4 gg = *(const float4*)&g[c];
  const float4 bev = *(const float4*)&be[c];
  float o0 = (vv[0] - mu) * rstd * gg.x + bev.x;
  float o1 = (vv[1] - mu) * rstd * gg.y + bev.y;
  float o2 = (vv[2] - mu) * rstd * gg.z + bev.z;
  float o3 = (vv[3] - mu) * rstd * gg.w + bev.w;
  if constexpr (EMIT_F32) {
    float4 yo = { o0, o1, o2, o3 };
    *(float4*)&y[row * 512 + c] = yo;
  }
  if constexpr (EMIT_BF16) {
    bf16x4 ob = { (bf16_t)o0, (bf16_t)o1, (bf16_t)o2, (bf16_t)o3 };
    *(bf16x4*)&yb[row * 512 + c] = ob;
  }
}

// ---------------------------------------------------------------------------
extern "C" void kernel_launch(void* const* d_in, const int* in_sizes, int n_in,
                              void* d_out, int out_size, void* d_ws, size_t ws_size,
                              hipStream_t stream)
{
  const float* x   = (const float*)d_in[0];
  const float* wq  = (const float*)d_in[1];
  const float* bq  = (const float*)d_in[2];
  const float* wk  = (const float*)d_in[3];
  const float* bk  = (const float*)d_in[4];
  const float* wv  = (const float*)d_in[5];
  const float* bv  = (const float*)d_in[6];
  const float* wp  = (const float*)d_in[7];
  const float* bp  = (const float*)d_in[8];
  const float* w1  = (const float*)d_in[9];
  const float* b1  = (const float*)d_in[10];
  const float* w2  = (const float*)d_in[11];
  const float* b2  = (const float*)d_in[12];
  const float* g1  = (const float*)d_in[13];
  const float* be1 = (const float*)d_in[14];
  const float* g2  = (const float*)d_in[15];
  const float* be2 = (const float*)d_in[16];

  const long S = 16L * 2048 * 512;   // tokens*D
  const long Mi = 1L << 20;

  // Workspace (200 MiB):
  //   0: weights (wqkvT 1.5, wpT 0.5, w1T 2, w2T 2, bqkv) -> 8 MiB region
  //   8: xb 32            (reused as ob after QKV)
  //  40: qkb 64 [32768][1024]  (reused: x1b at 40..72, h spans 72..200)
  // 104: vT 32 [16][512][2048]
  // 136: E  64 (8-batch score chunk; 2 passes)
  const size_t NEED = (size_t)200 * Mi;
  if (ws_size < NEED) return;

  char* wsp = (char*)d_ws;
  bf16_t* wqkvT = (bf16_t*)(wsp + 0);            // [1536][512]
  bf16_t* wpT   = wqkvT + 1536L * 512;           // [512][512]
  bf16_t* w1T   = wpT + 512L * 512;              // [2048][512]
  bf16_t* w2T   = w1T + 2048L * 512;             // [512][2048]
  float*  bqkv  = (float*)(w2T + 512L * 2048);   // [1536]
  bf16_t* xb  = (bf16_t*)(wsp +   8 * Mi);       // 32 MiB
  bf16_t* qkb = (bf16_t*)(wsp +  40 * Mi);       // 64 MiB [32768][1024]
  bf16_t* vT  = (bf16_t*)(wsp + 104 * Mi);       // 32 MiB
  bf16_t* E   = (bf16_t*)(wsp + 136 * Mi);       // 64 MiB
  bf16_t* ob  = xb;                              // PV out
  bf16_t* x1b = qkb;                             // 32 MiB at off 40
  bf16_t* h   = (bf16_t*)(wsp + 72 * Mi);        // 128 MiB [32768][2048]

  // 1. cast x -> bf16
  cast_to_bf16<<<dim3((unsigned)(S / 4 / 256)), 256, 0, stream>>>(x, xb, S);

  // 2. weight transposes + bias concat
  transpose_cast<<<dim3(16, 16), 256, 0, stream>>>(wq, wqkvT,               512, 512);
  transpose_cast<<<dim3(16, 16), 256, 0, stream>>>(wk, wqkvT + 512L * 512,  512, 512);
  transpose_cast<<<dim3(16, 16), 256, 0, stream>>>(wv, wqkvT + 1024L * 512, 512, 512);
  transpose_cast<<<dim3(16, 16), 256, 0, stream>>>(wp, wpT, 512, 512);
  transpose_cast<<<dim3(64, 16), 256, 0, stream>>>(w1, w1T, 512, 2048);
  transpose_cast<<<dim3(16, 64), 256, 0, stream>>>(w2, w2T, 2048, 512);
  concat_bias<<<dim3(6), 256, 0, stream>>>(bq, bk, bv, bqkv);

  // 3. merged QKV GEMM (M=32768, N=1536, K=512), split epilogue:
  //    cols<1024 -> qkb (ldc=1024); cols>=1024 -> vT transposed per batch
  gemm_bt<5, true><<<dim3(12, 256, 1), 256, 0, stream>>>(
      xb, wqkvT, bqkv, qkb, vT, 32768, 1536, 512, 512, 512, 1024, 0, 0, 0, 0.f);

  // 4. attention in 2 chunks of 8 batches
  for (int cgrp = 0; cgrp < 2; cgrp++) {
    const long qoff = (long)cgrp * 8 * 2048 * 1024;
    // E = (q k^T) * 1/sqrt(512)  (M=N=2048, K=512, z=8)
    gemm_bt<2, false><<<dim3(16, 16, 8), 256, 0, stream>>>(
        qkb + qoff, qkb + qoff + 512, nullptr, E, nullptr,
        2048, 2048, 512, 1024, 1024, 2048,
        2048L * 1024, 2048L * 1024, 2048L * 2048, 0.04419417382f);
    // softmax rows
    softmax2048<<<dim3(16384), 256, 0, stream>>>(E);
    // out = P V  (M=2048, N=512, K=2048, z=8)
    gemm_bt<1, false><<<dim3(4, 16, 8), 256, 0, stream>>>(
        E, vT + (long)cgrp * 8 * 512 * 2048, nullptr,
        ob + (long)cgrp * 8 * 2048 * 512, nullptr,
        2048, 512, 2048, 2048, 2048, 512,
        2048L * 2048, 512L * 2048, 2048L * 512, 0.f);
  }

  // 5. proj -> d_out (fp32 scratch)
  gemm_bt<0, true><<<dim3(4, 256, 1), 256, 0, stream>>>(
      ob, wpT, bp, (float*)d_out, nullptr,
      32768, 512, 512, 512, 512, 512, 0, 0, 0, 0.f);

  // 6. x1b = bf16( LN(x + proj) )
  add_ln<false, false, true><<<dim3(32768), 128, 0, stream>>>(
      x, (float*)d_out, g1, be1, nullptr, x1b);

  // 7. FF1: h = gelu(x1 w1 + b1)  (M=32768, N=2048, K=512)
  gemm_bt<3, true><<<dim3(16, 256, 1), 256, 0, stream>>>(
      x1b, w1T, b1, h, nullptr, 32768, 2048, 512, 512, 512, 2048, 0, 0, 0, 0.f);

  // 8. FF2: ff = h w2 + b2 -> d_out (fp32)  (M=32768, N=512, K=2048)
  gemm_bt<0, true><<<dim3(4, 256, 1), 256, 0, stream>>>(
      h, w2T, b2, (float*)d_out, nullptr,
      32768, 512, 2048, 2048, 2048, 512, 0, 0, 0, 0.f);

  // 9. out = LN(x1 + ff), in place on d_out
  add_ln<true, true, false><<<dim3(32768), 128, 0, stream>>>(
      x1b, (float*)d_out, g2, be2, (float*)d_out, nullptr);
}